// Round 14
// baseline (268.504 us; speedup 1.0000x reference)
//
#include <hip/hip_runtime.h>
#include <stdint.h>
#include <math.h>

#define NALPH 128
#define NEMB  128
#define NST   512
#define BATCH 256
#define TLEN  256
#define FANIN 640   // NEMB + NST

// No host/device-divergent preprocessor control flow (R11 lesson).
#define SDOT4(a, b, c) __builtin_amdgcn_sdot4((a), (b), (c), false)
typedef __attribute__((ext_vector_type(4))) int i32x4;

// LDS-only barrier, race-fixed (R18/R19 lessons): ONE asm statement holding
// both s_waitcnt lgkmcnt(0) and s_barrier with a "memory" clobber (s_barrier
// alone is IntrNoMem to LLVM — ds ops would be hoisted across it), plus
// sched_barrier(0) (rule #18). Omits the vmcnt(0) drain: per-step global
// qstates stores / G prefetches stay in flight across the barrier.
#define BAR_LDS() do {                                            \
    asm volatile("s_waitcnt lgkmcnt(0)\n\ts_barrier" ::: "memory"); \
    __builtin_amdgcn_sched_barrier(0);                            \
  } while (0)

// ---------------------------------------------------------------------------
// k_tr — tiny transpose: WfT[e*512+n] = W_in[n*640+e] (W_f part only).
// 512 blocks x 128 thr: block n reads its row coalesced (128 consecutive
// floats); writes scattered (256 KB total, L2-absorbed). Separate kernel so
// k_prep's G-branch can read WfT without a same-kernel write/read race.
// ---------------------------------------------------------------------------
__global__ __launch_bounds__(128) void k_tr(
    const float* __restrict__ W_in, float* __restrict__ WfT)
{
  int n = blockIdx.x, e = threadIdx.x;
  WfT[e * NST + n] = W_in[(size_t)n * FANIN + e];
}

// ---------------------------------------------------------------------------
// k_prep (896 blocks x 256 thr):
//  [0,256)    G[tok*512+n] = b_in[n] + sum_e emb[tok,e]*WfT[e][n]  (fp32, same
//             e-order/fmaf as before -> bit-identical G). R22: WfT access is
//             lane-coalesced — R21's float4-on-rows was a null because each
//             LANE owned a different 2560B-strided row (64 lines/instr either
//             way); transposition is the actual coalescing fix.
//  [256,768)  W_s row-quant -> WsF MFMA B-frag only (WqT dead, deleted); Sd
//  [768,896)  W_out row-quant -> WoF frag order only (WoQ dead, deleted); So
// Frag formula (dword kd of row r): c=kd>>4, hi=(kd>>2)&3, d=kd&3,
// lane=hi*16+(r&15), tile=r>>4 — HW-validated bit-exact by R12/R15/R17/R20.
// ---------------------------------------------------------------------------
__global__ __launch_bounds__(256) void k_prep(
    const float* __restrict__ emb, const float* __restrict__ W_in,
    const float* __restrict__ b_in, const float* __restrict__ W_out,
    const float* __restrict__ WfT,
    float* __restrict__ G, float* __restrict__ Sd,
    int* __restrict__ WoF, float* __restrict__ So,
    int* __restrict__ WsF)
{
  int bid = blockIdx.x, tid = threadIdx.x;
  if (bid < 256) {
    int tok = bid >> 1;                    // uniform per block (scalar loads)
    int n   = ((bid & 1) << 8) + tid;      // lane-consecutive
    const float* eb = emb + tok * NEMB;
    float acc = b_in[n];
#pragma unroll 8
    for (int e = 0; e < NEMB; ++e)
      acc = fmaf(eb[e], WfT[e * NST + n], acc);   // WfT: coalesced across lanes
    G[tok * NST + n] = acc;
  } else if (bid < 768) {
    int n = bid - 256;                   // W_s row
    __shared__ float smax[128];
    float lw[4]; float m = 0.f;
    if (tid < 128) {
      float4 v = *(const float4*)(W_in + (size_t)n * FANIN + NEMB + tid * 4);
      lw[0] = v.x; lw[1] = v.y; lw[2] = v.z; lw[3] = v.w;
#pragma unroll
      for (int i = 0; i < 4; ++i) m = fmaxf(m, fabsf(lw[i]));
      smax[tid] = m;
    }
    __syncthreads();
    for (int s2 = 64; s2 > 0; s2 >>= 1) {
      if (tid < s2) smax[tid] = fmaxf(smax[tid], smax[tid + s2]);
      __syncthreads();
    }
    float mx = smax[0];
    if (tid < 128) {
      float r = 127.f / mx;
      uint32_t pk = 0;
#pragma unroll
      for (int i = 0; i < 4; ++i) {
        int qv = (int)rintf(lw[i] * r);
        qv = qv < -127 ? -127 : (qv > 127 ? 127 : qv);
        pk |= (uint32_t)(qv & 0xff) << (8 * i);
      }
      int kd = tid;
      int c = kd >> 4, hi = (kd >> 2) & 3, d = kd & 3;
      int lane = hi * 16 + (n & 15), nt = n >> 4;
      WsF[(((nt * 8 + c) * 64) + lane) * 4 + d] = (int)pk;  // MFMA B-frag
    }
    if (tid == 0) Sd[n] = mx / 16129.0f;
  } else {
    int a = bid - 768;                   // W_out row
    __shared__ float smax[128];
    float lw[4]; float m = 0.f;
    if (tid < 128) {
      float4 v = *(const float4*)(W_out + (size_t)a * NST + tid * 4);
      lw[0] = v.x; lw[1] = v.y; lw[2] = v.z; lw[3] = v.w;
#pragma unroll
      for (int i = 0; i < 4; ++i) m = fmaxf(m, fabsf(lw[i]));
      smax[tid] = m;
    }
    __syncthreads();
    for (int s2 = 64; s2 > 0; s2 >>= 1) {
      if (tid < s2) smax[tid] = fmaxf(smax[tid], smax[tid + s2]);
      __syncthreads();
    }
    float mx = smax[0];
    if (tid < 128) {
      float r = 127.f / mx;
      uint32_t pk = 0;
#pragma unroll
      for (int i = 0; i < 4; ++i) {
        int qv = (int)rintf(lw[i] * r);
        qv = qv < -127 ? -127 : (qv > 127 ? 127 : qv);
        pk |= (uint32_t)(qv & 0xff) << (8 * i);
      }
      int kd = tid;
      int c = kd >> 4, hi = (kd >> 2) & 3, d = kd & 3;
      int lane = hi * 16 + (a & 15), ta = a >> 4;
      WoF[(((ta * 8 + c) * 64) + lane) * 4 + d] = (int)pk;  // MFMA B-frag
    }
    if (tid == 0) So[a] = mx / 16129.0f;
  }
}

// ---------------------------------------------------------------------------
// k_rec — R21 verbatim (196.8-197.7 us, MfmaUtil ~59%): full-K MFMA engine +
// BAR_LDS + lane-local merge. Wall: 1306 cyc/SIMD matrix issue (structural,
// M-batching is S-invariant) + ~540 cyc tail.
// ---------------------------------------------------------------------------
__global__ __launch_bounds__(512, 1) void k_rec(
    const int* __restrict__ w, const float* __restrict__ G,
    const int* __restrict__ WsF, const float* __restrict__ Sd,
    signed char* __restrict__ qstates)
{
  __shared__ __align__(16) signed char qs[2][NST];
  int tid  = threadIdx.x;
  int lane = tid & 63, wv = tid >> 6;
  int l15  = lane & 15, hi = lane >> 4;
  int row  = blockIdx.x;

  const i32x4* wsf = (const i32x4*)WsF;
  i32x4 Bf[4][8];
#pragma unroll
  for (int q = 0; q < 4; ++q)
#pragma unroll
    for (int c = 0; c < 8; ++c)
      Bf[q][c] = wsf[((size_t)((wv * 4 + q) * 8 + c)) * 64 + lane];

  float dn = Sd[tid];
  const int* wr = w + row * TLEN;
  float g = G[wr[0] * NST + tid];

  qs[0][tid] = 0;
  __syncthreads();

  signed char* qrow = qstates + (size_t)row * TLEN * NST + tid;

  int p = 0;
  for (int t = 0; t < TLEN; ++t) {
    int tok_n = (t < TLEN - 1) ? wr[t + 1] : 0;
    float g_n = G[tok_n * NST + tid];    // prefetch; stays in flight past BAR

    i32x4 A[8];
#pragma unroll
    for (int c = 0; c < 8; ++c)
      A[c] = *(const i32x4*)(qs[p] + c * 64 + hi * 16);

    i32x4 acc0 = {0,0,0,0}, acc1 = {0,0,0,0}, acc2 = {0,0,0,0}, acc3 = {0,0,0,0};
#pragma unroll
    for (int c = 0; c < 8; ++c) {
      acc0 = __builtin_amdgcn_mfma_i32_16x16x64_i8(A[c], Bf[0][c], acc0, 0, 0, 0);
      acc1 = __builtin_amdgcn_mfma_i32_16x16x64_i8(A[c], Bf[1][c], acc1, 0, 0, 0);
      acc2 = __builtin_amdgcn_mfma_i32_16x16x64_i8(A[c], Bf[2][c], acc2, 0, 0, 0);
      acc3 = __builtin_amdgcn_mfma_i32_16x16x64_i8(A[c], Bf[3][c], acc3, 0, 0, 0);
    }

    int vm = (hi & 1) ? ((hi & 2) ? acc3[0] : acc1[0])
                      : ((hi & 2) ? acc2[0] : acc0[0]);

    float a = g + (float)vm * dn;
    a = fminf(fmaxf(a, -15.f), 15.f);
    float e = __expf(2.f * a);           // tanh = 1 - 2/(e^(2a)+1)
    float s = fmaf(-2.f, __builtin_amdgcn_rcpf(e + 1.f), 1.f);
    signed char q8 = (signed char)(int)rintf(s * 127.f);
    qs[p ^ 1][tid] = q8;                 // LDS first: barrier waits on this
    qrow[(size_t)t * NST] = q8;          // fire-and-forget; no vmcnt wait
    BAR_LDS();
    g = g_n;
    p ^= 1;
  }
}

// ---------------------------------------------------------------------------
// k_out_mfma R22 — compute identical to R15's proven version; stores now
// staged through LDS: the direct store wrote 1 dword/lane as 16B row
// segments (partial lines); LDS-staging converts the flush into fully
// contiguous float4 stores (32 KB/block, 4 blocks/CU preserved).
// ---------------------------------------------------------------------------
__global__ __launch_bounds__(256) void k_out_mfma(
    const signed char* __restrict__ qstates, const int* __restrict__ WoF,
    const float* __restrict__ So, const float* __restrict__ b_out,
    float* __restrict__ y)
{
  __shared__ float sl[64 * 128];         // 32 KB staging
  int tid = threadIdx.x;
  int lane = tid & 63, wv = tid >> 6;
  int l15 = lane & 15, hi = lane >> 4;
  size_t bt0 = (size_t)blockIdx.x * 64 + (size_t)wv * 16;

  const signed char* abase = qstates + (bt0 + l15) * NST + hi * 16;
  i32x4 A[8];
#pragma unroll
  for (int c = 0; c < 8; ++c) A[c] = *(const i32x4*)(abase + c * 64);

  const i32x4* wf = (const i32x4*)WoF;
#pragma unroll
  for (int ta = 0; ta < 8; ++ta) {
    const i32x4* bbase = wf + (size_t)ta * 8 * 64 + lane;
    i32x4 acc = {0, 0, 0, 0};
#pragma unroll
    for (int c = 0; c < 8; ++c)
      acc = __builtin_amdgcn_mfma_i32_16x16x64_i8(A[c], bbase[c * 64], acc, 0, 0, 0);
    int a = ta * 16 + l15;
    float s = So[a], b = b_out[a];
    float* slb = sl + (wv * 16 + hi * 4) * 128 + a;
#pragma unroll
    for (int r = 0; r < 4; ++r) slb[r * 128] = (float)acc[r] * s + b;
  }
  __syncthreads();

  // Coalesced flush: 64 rows x 128 cols = 8192 floats = 2048 float4.
  float4* yb = (float4*)(y + (size_t)blockIdx.x * 64 * 128);
  const float4* sb = (const float4*)sl;
#pragma unroll
  for (int i = 0; i < 8; ++i) yb[i * 256 + tid] = sb[i * 256 + tid];
}

// ---------------------------------------------------------------------------
extern "C" void kernel_launch(void* const* d_in, const int* in_sizes, int n_in,
                              void* d_out, int out_size, void* d_ws, size_t ws_size,
                              hipStream_t stream) {
  const int*   w     = (const int*)d_in[0];
  const float* emb   = (const float*)d_in[1];
  const float* W_in  = (const float*)d_in[2];
  const float* b_in  = (const float*)d_in[3];
  const float* W_out = (const float*)d_in[4];
  const float* b_out = (const float*)d_in[5];
  float* y = (float*)d_out;

  // Workspace map (WqT/WoQ slots retired; WfT reuses WqT's 256 KB):
  //   [0,256K)     G
  //   [256K,512K)  WfT   (256 KB transposed W_f)
  //   [512K,514K)  Sd
  //   [640K,641K)  So
  //   [704K,768K)  WoF   (64 KB, frag-order — R16 size lesson)
  //   [768K,1024K) WsF   (256 KB, frag-order) — ends exactly at qstates
  //   [1024K,+32M) qstates
  char* ws = (char*)d_ws;
  float*       G       = (float*)ws;
  float*       WfT     = (float*)(ws + (256 << 10));
  float*       Sd      = (float*)(ws + (512 << 10));
  float*       So      = (float*)(ws + (640 << 10));
  int*         WoF     = (int*)(ws + (704 << 10));
  int*         WsF     = (int*)(ws + (768 << 10));
  signed char* qstates = (signed char*)(ws + (1024 << 10));

  k_tr  <<<512, 128, 0, stream>>>(W_in, WfT);
  k_prep<<<896, 256, 0, stream>>>(emb, W_in, b_in, W_out, WfT, G, Sd, WoF, So, WsF);
  k_rec <<<BATCH, 512, 0, stream>>>(w, G, WsF, Sd, qstates);
  k_out_mfma<<<BATCH * TLEN / 64, 256, 0, stream>>>(qstates, WoF, So, b_out, y);
}